// Round 4
// baseline (196.554 us; speedup 1.0000x reference)
//
#include <hip/hip_runtime.h>

// Problem constants (B,C,H,W = 32,512,32,32; S = 512)
#define NB 32
#define NC 512
#define NS 512
#define HW 1024          // H*W
#define P  16            // pixels per block
#define BLOCK 256
#define ST 516           // LDS row stride in floats (multiple of 4 -> float4 aligned)
#define NBLK 2048        // (NB*HW)/P

// Bijective swizzle: XOR bits 6-8 of c into bits 2-4. Low 2 bits preserved and
// swz(c4+k)=swz(c4)+k within a 4-aligned group -> float4 accesses stay
// contiguous and 16B-aligned. Spreads the structured binary-search probe
// positions (all == 2^k-1 mod 32 for steps >= 32) across banks.
__device__ __forceinline__ int swz(int c) { return c ^ ((c >> 4) & 28); }

__global__ __launch_bounds__(BLOCK, 4) void spike_kernel(
    const float* __restrict__ x,
    const float* __restrict__ rv,
    int* __restrict__ out)
{
    __shared__ float cdf[P * ST];   // [px][swz(c)] normalized CDF
    __shared__ float tot[P];

    const int tid = threadIdx.x;
    // Chunked XCD swizzle: consecutive logical blocks (sharing 128B lines of
    // x/rv/out) stay on one XCD's L2.
    const int bid = blockIdx.x;
    const int logical = (bid & 7) * (NBLK / 8) + (bid >> 3);
    const int pix = logical * P;            // global pixel base (16-aligned)
    const int b  = pix >> 10;               // / HW
    const int hw = pix & (HW - 1);
    const float* xb = x + (size_t)b * NC * HW + hw;

    // ---------- phase 0: stage x into LDS with all 256 threads ----------
    // Each thread: 8 independent float4 loads (4 pixels x 1 channel each) ->
    // enough VMEM in flight to pace HBM.
    {
        const int cq  = tid >> 2;           // 0..63
        const int px4 = (tid & 3) * 4;      // 0,4,8,12
        #pragma unroll
        for (int p = 0; p < 8; ++p) {
            const int c = p * 64 + cq;
            const float4 v = *(const float4*)(xb + (size_t)c * HW + px4);
            const int sc = swz(c);
            // 4 scalar LDS writes to 4 pixel rows: 2 lanes/bank max -> free.
            cdf[(px4 + 0) * ST + sc] = v.x;
            cdf[(px4 + 1) * ST + sc] = v.y;
            cdf[(px4 + 2) * ST + sc] = v.z;
            cdf[(px4 + 3) * ST + sc] = v.w;
        }
    }
    __syncthreads();

    // ---------- phase 1: exact sequential fold-left cumsum (from LDS) ----------
    // One lane per pixel; ds_read_b128/ds_write_b128 amortize the LDS pipe.
    // Rounding order identical to np/jnp f32 cumsum (left-nested fold).
    if (tid < P) {
        float* row = cdf + tid * ST;
        float run = 0.f;
        #pragma unroll 4
        for (int c4 = 0; c4 < NC; c4 += 4) {
            float4 v = *(float4*)(row + swz(c4));
            float s0 = run + v.x;
            float s1 = s0 + v.y;
            float s2 = s1 + v.z;
            float s3 = s2 + v.w;
            run = s3;
            *(float4*)(row + swz(c4)) = make_float4(s0, s1, s2, s3);
        }
        tot[tid] = run;                     // unnormalized cdf[511]
    }
    __syncthreads();

    // ---------- phase 2: normalize, exact IEEE f32 division ----------
    // Iterate storage order (swz is a bijection of [0,512) -> elementwise ok).
    #pragma unroll
    for (int k = 0; k < 8; ++k) {
        const int flat = tid + k * BLOCK;   // float4-group index, 0..2047
        const int px = flat >> 7;
        const int g  = flat & 127;
        const float t = tot[px];
        float4* ptr = (float4*)(cdf + px * ST + g * 4);
        float4 v = *ptr;
        v.x = v.x / t; v.y = v.y / t; v.z = v.z / t; v.w = v.w / t;
        *ptr = v;                           // cdf[511]/t == 1.0 exactly
    }
    __syncthreads();

    // ---------- phase 3: searches; top 4 levels from registers ----------
    const int px  = tid & (P - 1);
    const int sof = tid >> 4;               // 0..15
    const float* row = cdf + px * ST;
    // Register cache of binary-search levels 1-4 (15 values, fixed positions).
    const float r255 = row[swz(255)];
    const float r127 = row[swz(127)], r383 = row[swz(383)];
    const float r63  = row[swz(63)],  r191 = row[swz(191)];
    const float r319 = row[swz(319)], r447 = row[swz(447)];
    const float r31  = row[swz(31)],  r95  = row[swz(95)];
    const float r159 = row[swz(159)], r223 = row[swz(223)];
    const float r287 = row[swz(287)], r351 = row[swz(351)];
    const float r415 = row[swz(415)], r479 = row[swz(479)];

    const size_t io_base = (size_t)b * NS * HW + hw + px;
    #pragma unroll 4
    for (int si = 0; si < 32; ++si) {
        const int s = si * 16 + sof;
        const size_t off = io_base + (size_t)s * HW;
        const float u = rv[off];
        // Branchless mux-tree = first 4 iterations of lower_bound (steps 256..32).
        const bool  b0 = r255 < u;
        const float p1 = b0 ? r383 : r127;
        const bool  b1 = p1 < u;
        const float p2a = b1 ? r191 : r63;
        const float p2b = b1 ? r447 : r319;
        const float p2  = b0 ? p2b : p2a;
        const bool  b2 = p2 < u;
        const float q0 = b2 ? r95  : r31;
        const float q1 = b2 ? r223 : r159;
        const float q2 = b2 ? r351 : r287;
        const float q3 = b2 ? r479 : r415;
        const float q01 = b1 ? q1 : q0;
        const float q23 = b1 ? q3 : q2;
        const float p3  = b0 ? q23 : q01;
        const bool  b3 = p3 < u;
        int pos = (b0 ? 256 : 0) | (b1 ? 128 : 0) | (b2 ? 64 : 0) | (b3 ? 32 : 0);
        // Remaining 5 levels from LDS (steps 16..1), identical predicate.
        #pragma unroll
        for (int step = 16; step > 0; step >>= 1) {
            const float a = row[swz(pos + step - 1)];
            pos += (a < u) ? step : 0;
        }
        out[off] = pos;                     // int32 index (harness reads np.int32)
    }
}

extern "C" void kernel_launch(void* const* d_in, const int* in_sizes, int n_in,
                              void* d_out, int out_size, void* d_ws, size_t ws_size,
                              hipStream_t stream) {
    const float* x  = (const float*)d_in[0];   // [B, C, H, W] f32
    const float* rv = (const float*)d_in[1];   // [B, S, H, W] f32
    int* out = (int*)d_out;                    // [B, S, H, W] int32 indices

    spike_kernel<<<dim3(NBLK), dim3(BLOCK), 0, stream>>>(x, rv, out);
}

// Round 10
// 188.919 us; speedup vs baseline: 1.0404x; 1.0404x over previous
//
#include <hip/hip_runtime.h>

// Problem constants (B,C,H,W = 32,512,32,32; S = 512)
#define NB 32
#define NC 512
#define NS 512
#define HW 1024          // H*W
#define P  16            // pixels per block
#define BLOCK 256
#define NBLK 2048        // (NB*HW)/P

// LDS layout: c-major, cdf[c*P + px].
// Bank(c,px) = (c*16 + px) % 32 = px + 16*(c&1):
//  - binary-search probes: lanes with different px NEVER collide; the 4
//    same-px lanes split by c-parity -> ~2-way (free).
//  - register-cache loads (same c, all px): 16 banks + broadcast -> free.
//  - cumsum writes: 4 same-px lanes same bank -> 4-way on 128 wave-writes
//    (~+400 cy/block, accepted).
__global__ __launch_bounds__(BLOCK, 4) void spike_kernel(
    const float* __restrict__ x,
    const float* __restrict__ rv,
    int* __restrict__ out)
{
    __shared__ float cdf[NC * P];   // 32 KiB, unnormalized CDF, c-major
    __shared__ float wtot[4 * P];   // per-wave per-pixel segment totals
    __shared__ float tot[P];        // unnormalized cdf[511] per pixel

    const int tid  = threadIdx.x;
    const int lane = tid & 63;
    const int wv   = tid >> 6;              // wave 0..3
    // Chunked XCD swizzle: consecutive logical blocks (sharing 128B lines of
    // x/rv/out) stay on one XCD's L2.
    const int bid = blockIdx.x;
    const int logical = (bid & 7) * (NBLK / 8) + (bid >> 3);
    const int pix = logical * P;            // global pixel base (16-aligned)
    const int b  = pix >> 10;               // / HW
    const int hw = pix & (HW - 1);

    const int px  = tid & 15;               // pixel within block
    const int seg = tid >> 4;               // channel segment 0..15 (32 ch each)

    // ---------- phase 1a: load 32 channels straight to registers, sum ----------
    // Wave-load = 4 x 64B segments; 32 independent loads in flight per thread.
    const float* xp = x + (size_t)b * NC * HW + (size_t)(seg * 32) * HW + hw + px;
    float xs[32];
    #pragma unroll
    for (int i = 0; i < 32; ++i) xs[i] = xp[(size_t)i * HW];
    float ssum = 0.f;
    #pragma unroll
    for (int i = 0; i < 32; ++i) ssum += xs[i];

    // Inclusive prefix over the 4 segment-groups within this wave (same px is
    // 16 lanes apart): Hillis-Steele via shfl_up.
    float incl = ssum;
    float t1 = __shfl_up(incl, 16, 64); incl += (lane >= 16) ? t1 : 0.f;
    float t2 = __shfl_up(incl, 32, 64); incl += (lane >= 32) ? t2 : 0.f;
    if (lane >= 48) wtot[wv * P + px] = incl;   // wave-inclusive totals (16 px)
    __syncthreads();

    // Exclusive offset = intra-wave exclusive + totals of preceding waves.
    float excl = incl - ssum;
    for (int w = 0; w < wv; ++w) excl += wtot[w * P + px];  // wave-uniform trip

    // ---------- phase 1b: write running cumsum (c-major) ----------
    float run = excl;
    float* cbase = cdf + seg * 32 * P + px;
    #pragma unroll
    for (int i = 0; i < 32; ++i) { run += xs[i]; cbase[i * P] = run; }
    if (seg == 15) tot[px] = run;           // grand total (== raw cdf[511])
    __syncthreads();

    // ---------- phase 2: binary searches on UNNORMALIZED cdf ----------
    // Normalization fused: compare cdf_raw[i] < u*tot  (== cdf[i]/tot < u up
    // to rounding; +-1 index at boundaries, inside tolerance).
    const int sof = seg;                    // spike offset 0..15
    const float to = tot[px];
    // Register cache of search levels 1-4 (steps 256..32): 15 fixed positions.
    #define RC(p_) cdf[(p_) * P + px]
    const float r255 = RC(255);
    const float r127 = RC(127), r383 = RC(383);
    const float r63  = RC(63),  r191 = RC(191);
    const float r319 = RC(319), r447 = RC(447);
    const float r31  = RC(31),  r95  = RC(95);
    const float r159 = RC(159), r223 = RC(223);
    const float r287 = RC(287), r351 = RC(351);
    const float r415 = RC(415), r479 = RC(479);
    #undef RC

    const size_t io_base = (size_t)b * NS * HW + hw + px;
    #pragma unroll 4
    for (int si = 0; si < 32; ++si) {
        const int s = si * 16 + sof;
        const size_t off = io_base + (size_t)s * HW;
        const float u = rv[off] * to;       // scaled target
        // Branchless mux-tree = first 4 lower_bound iterations (steps 256..32).
        const bool  b0 = r255 < u;
        const float p1 = b0 ? r383 : r127;
        const bool  b1 = p1 < u;
        const float p2a = b1 ? r191 : r63;
        const float p2b = b1 ? r447 : r319;
        const float p2  = b0 ? p2b : p2a;
        const bool  b2 = p2 < u;
        const float q0 = b2 ? r95  : r31;
        const float q1 = b2 ? r223 : r159;
        const float q2 = b2 ? r351 : r287;
        const float q3 = b2 ? r479 : r415;
        const float q01 = b1 ? q1 : q0;
        const float q23 = b1 ? q3 : q2;
        const float p3  = b0 ? q23 : q01;
        const bool  b3 = p3 < u;
        int pos = (b0 ? 256 : 0) | (b1 ? 128 : 0) | (b2 ? 64 : 0) | (b3 ? 32 : 0);
        // Remaining 5 levels from LDS (steps 16..1), same predicate (side='left').
        #pragma unroll
        for (int step = 16; step > 0; step >>= 1) {
            const float a = cdf[(pos + step - 1) * P + px];
            pos += (a < u) ? step : 0;
        }
        out[off] = pos;                     // int32 index (harness reads np.int32)
    }
}

extern "C" void kernel_launch(void* const* d_in, const int* in_sizes, int n_in,
                              void* d_out, int out_size, void* d_ws, size_t ws_size,
                              hipStream_t stream) {
    const float* x  = (const float*)d_in[0];   // [B, C, H, W] f32
    const float* rv = (const float*)d_in[1];   // [B, S, H, W] f32
    int* out = (int*)d_out;                    // [B, S, H, W] int32 indices

    spike_kernel<<<dim3(NBLK), dim3(BLOCK), 0, stream>>>(x, rv, out);
}

// Round 13
// 188.709 us; speedup vs baseline: 1.0416x; 1.0011x over previous
//
#include <hip/hip_runtime.h>

// Problem constants (B,C,H,W = 32,512,32,32; S = 512)
#define NB 32
#define NC 512
#define NS 512
#define HW 1024          // H*W
#define P  16            // pixels per block
#define BLOCK 256
#define NBLK 2048        // (NB*HW)/P

// LDS layout: c-major, cdf[c*P + px]. Bank(c,px) = px + 16*(c&1):
// search probes conflict-free across px, ~2-way within same-px group (free);
// register-cache loads broadcast; cumsum writes 4-way on 128 wave-writes
// (measured residual: 1.5k conflict-cycles/block, negligible).
__global__ __launch_bounds__(BLOCK, 4) void spike_kernel(
    const float* __restrict__ x,
    const float* __restrict__ rv,
    int* __restrict__ out)
{
    __shared__ float cdf[NC * P];   // 32 KiB, unnormalized CDF, c-major
    __shared__ float wtot[4 * P];   // per-wave per-pixel segment totals
    __shared__ float tot[P];        // unnormalized cdf[511] per pixel

    const int tid  = threadIdx.x;
    const int lane = tid & 63;
    const int wv   = tid >> 6;              // wave 0..3
    // Chunked XCD swizzle: consecutive logical blocks share L2.
    const int bid = blockIdx.x;
    const int logical = (bid & 7) * (NBLK / 8) + (bid >> 3);
    const int pix = logical * P;            // global pixel base (16-aligned)
    const int b  = pix >> 10;               // / HW
    const int hw = pix & (HW - 1);

    const int px  = tid & 15;               // pixel within block
    const int seg = tid >> 4;               // channel segment 0..15 (32 ch each)

    // ---------- phase 0: issue BOTH load batches up front ----------
    // 32 x-loads (needed first) + 32 rv-loads (needed after the barrier):
    // ~64 independent loads in flight per thread. The scan below only drains
    // the x batch; rv latency hides under scan+cdf-write+barrier.
    const float* xp = x + (size_t)b * NC * HW + (size_t)(seg * 32) * HW + hw + px;
    float xs[32];
    #pragma unroll
    for (int i = 0; i < 32; ++i) xs[i] = xp[(size_t)i * HW];

    const int sof = seg;                    // spike offset 0..15
    const size_t io_base = (size_t)b * NS * HW + hw + px;
    float u[32];
    #pragma unroll
    for (int si = 0; si < 32; ++si)
        u[si] = rv[io_base + (size_t)(si * 16 + sof) * HW];

    // ---------- phase 1a: per-thread segment sum + cross-segment scan ----------
    float ssum = 0.f;
    #pragma unroll
    for (int i = 0; i < 32; ++i) ssum += xs[i];

    // Inclusive prefix over the 4 segment-groups within this wave (same px is
    // 16 lanes apart): Hillis-Steele via shfl_up.
    float incl = ssum;
    float t1 = __shfl_up(incl, 16, 64); incl += (lane >= 16) ? t1 : 0.f;
    float t2 = __shfl_up(incl, 32, 64); incl += (lane >= 32) ? t2 : 0.f;
    if (lane >= 48) wtot[wv * P + px] = incl;   // wave-inclusive totals (16 px)
    __syncthreads();

    // Exclusive offset = intra-wave exclusive + totals of preceding waves.
    float excl = incl - ssum;
    for (int w = 0; w < wv; ++w) excl += wtot[w * P + px];  // wave-uniform trip

    // ---------- phase 1b: write running cumsum (c-major) ----------
    float run = excl;
    float* cbase = cdf + seg * 32 * P + px;
    #pragma unroll
    for (int i = 0; i < 32; ++i) { run += xs[i]; cbase[i * P] = run; }
    if (seg == 15) tot[px] = run;           // grand total (== raw cdf[511])
    __syncthreads();

    // ---------- phase 2: binary searches on UNNORMALIZED cdf ----------
    // Normalization fused: cdf_raw[i] < u*tot  (== cdf[i]/tot < u up to
    // rounding; +-1 index at boundaries, inside the 10.24 tolerance).
    const float to = tot[px];
    // Register cache of search levels 1-4 (steps 256..32): 15 fixed positions.
    #define RC(p_) cdf[(p_) * P + px]
    const float r255 = RC(255);
    const float r127 = RC(127), r383 = RC(383);
    const float r63  = RC(63),  r191 = RC(191);
    const float r319 = RC(319), r447 = RC(447);
    const float r31  = RC(31),  r95  = RC(95);
    const float r159 = RC(159), r223 = RC(223);
    const float r287 = RC(287), r351 = RC(351);
    const float r415 = RC(415), r479 = RC(479);
    #undef RC

    // Fully unrolled: all 32 searches' LDS chains interleave (static u[] idx).
    #pragma unroll
    for (int si = 0; si < 32; ++si) {
        const float us = u[si] * to;        // scaled target
        // Branchless mux-tree = first 4 lower_bound iterations (steps 256..32).
        const bool  b0 = r255 < us;
        const float p1 = b0 ? r383 : r127;
        const bool  b1 = p1 < us;
        const float p2a = b1 ? r191 : r63;
        const float p2b = b1 ? r447 : r319;
        const float p2  = b0 ? p2b : p2a;
        const bool  b2 = p2 < us;
        const float q0 = b2 ? r95  : r31;
        const float q1 = b2 ? r223 : r159;
        const float q2 = b2 ? r351 : r287;
        const float q3 = b2 ? r479 : r415;
        const float q01 = b1 ? q1 : q0;
        const float q23 = b1 ? q3 : q2;
        const float p3  = b0 ? q23 : q01;
        const bool  b3 = p3 < us;
        int pos = (b0 ? 256 : 0) | (b1 ? 128 : 0) | (b2 ? 64 : 0) | (b3 ? 32 : 0);
        // Remaining 5 levels from LDS (steps 16..1), same predicate (side='left').
        #pragma unroll
        for (int step = 16; step > 0; step >>= 1) {
            const float a = cdf[(pos + step - 1) * P + px];
            pos += (a < us) ? step : 0;
        }
        out[io_base + (size_t)(si * 16 + sof) * HW] = pos;  // int32 index
    }
}

extern "C" void kernel_launch(void* const* d_in, const int* in_sizes, int n_in,
                              void* d_out, int out_size, void* d_ws, size_t ws_size,
                              hipStream_t stream) {
    const float* x  = (const float*)d_in[0];   // [B, C, H, W] f32
    const float* rv = (const float*)d_in[1];   // [B, S, H, W] f32
    int* out = (int*)d_out;                    // [B, S, H, W] int32 indices

    spike_kernel<<<dim3(NBLK), dim3(BLOCK), 0, stream>>>(x, rv, out);
}